// Round 2
// 1395.080 us; speedup vs baseline: 1.0309x; 1.0309x over previous
//
#include <hip/hip_runtime.h>

#define N_NODES 100000
#define N_EDGES 3200000
#define IN_F 500
#define HID 64
#define OUT_F 64
#define ALPHA 0.1f
#define K_ITERS 10
#define SCAN_B ((N_NODES + 255) / 256)   // 391

#define NPART 8                 // XCD count (m09)
#define PART_N (N_NODES / NPART)         // 12500
#define FILL_GRID 2048          // 8 blocks/CU x 256 CU -> fully resident

typedef unsigned short ushort_t;
typedef unsigned int uint_t;
typedef int iv4 __attribute__((ext_vector_type(4)));   // native vec: OK for nontemporal builtins

__device__ __forceinline__ float bf2f(ushort_t v) {
    union { uint_t u; float f; } c; c.u = ((uint_t)v) << 16; return c.f;
}
__device__ __forceinline__ ushort_t f2b(float f) {
    union { float f; uint_t u; } c; c.f = f;
    uint_t u = c.u + 0x7fffu + ((c.u >> 16) & 1u);   // round-to-nearest-even
    return (ushort_t)(u >> 16);
}
__device__ __forceinline__ float bflo(uint_t u) {
    union { uint_t u; float f; } c; c.u = u << 16; return c.f;
}
__device__ __forceinline__ float bfhi(uint_t u) {
    union { uint_t u; float f; } c; c.u = u & 0xffff0000u; return c.f;
}
__device__ __forceinline__ uint_t packbf(float a, float b) {
    return (uint_t)f2b(a) | ((uint_t)f2b(b) << 16);
}

// ---------------------------------------------------------------------------
// Fused MLP: v = relu(x@W1+b1)@W2+b2 ; writes hb = bf16(v), ahb = bf16(ALPHA*v)
// Block = 256 = 4 waves; 32 rows x 64 cols; wave rg does rows rg*8..+7.
// W1/W2 read from global (L1-hot); only x and hid staged in LDS (20.8 KB ->
// 7 blocks/CU occupancy).
// ---------------------------------------------------------------------------
__global__ __launch_bounds__(256) void mlp_kernel(
    const float* __restrict__ x, const float* __restrict__ W1,
    const float* __restrict__ b1, const float* __restrict__ W2,
    const float* __restrict__ b2, ushort_t* __restrict__ hb,
    ushort_t* __restrict__ ahb)
{
    __shared__ float xs[32][100];   // 12.8 KB
    __shared__ float hid[32][64];   // 8 KB

    const int tid = threadIdx.x;
    const int c   = tid & 63;
    const int rg  = tid >> 6;
    const int block_row = blockIdx.x * 32;   // 3125*32 == 100000

    float acc[8] = {0.f, 0.f, 0.f, 0.f, 0.f, 0.f, 0.f, 0.f};

    for (int kb = 0; kb < IN_F; kb += 100) {
        for (int i = tid; i < 800; i += 256) {
            int r = i / 25, c4 = i - r * 25;
            *(float4*)&xs[r][c4 * 4] =
                *(const float4*)&x[(long)(block_row + r) * IN_F + kb + c4 * 4];
        }
        __syncthreads();
        for (int k = 0; k < 100; k += 4) {
            float w0 = W1[(kb+k+0)*HID + c];
            float w1 = W1[(kb+k+1)*HID + c];
            float w2 = W1[(kb+k+2)*HID + c];
            float w3 = W1[(kb+k+3)*HID + c];
            #pragma unroll
            for (int r = 0; r < 8; ++r) {
                float4 xv = *(const float4*)&xs[rg*8+r][k];
                acc[r] = fmaf(xv.x, w0, acc[r]);
                acc[r] = fmaf(xv.y, w1, acc[r]);
                acc[r] = fmaf(xv.z, w2, acc[r]);
                acc[r] = fmaf(xv.w, w3, acc[r]);
            }
        }
        __syncthreads();
    }

    float b = b1[c];
    #pragma unroll
    for (int r = 0; r < 8; ++r)
        hid[rg*8+r][c] = fmaxf(acc[r] + b, 0.f);
    __syncthreads();

    float o[8] = {0.f, 0.f, 0.f, 0.f, 0.f, 0.f, 0.f, 0.f};
    for (int k = 0; k < HID; k += 4) {
        float w0 = W2[(k+0)*OUT_F + c], w1 = W2[(k+1)*OUT_F + c];
        float w2 = W2[(k+2)*OUT_F + c], w3 = W2[(k+3)*OUT_F + c];
        #pragma unroll
        for (int r = 0; r < 8; ++r) {
            float4 hv = *(const float4*)&hid[rg*8+r][k];
            o[r] = fmaf(hv.x, w0, o[r]);
            o[r] = fmaf(hv.y, w1, o[r]);
            o[r] = fmaf(hv.z, w2, o[r]);
            o[r] = fmaf(hv.w, w3, o[r]);
        }
    }
    float bb = b2[c];
    int r0 = block_row + rg * 8;
    #pragma unroll
    for (int r = 0; r < 8; ++r) {
        float v = o[r] + bb;
        hb[(r0+r)*64 + c]  = f2b(v);
        ahb[(r0+r)*64 + c] = f2b(ALPHA * v);
    }
}

// ---------------------------------------------------------------------------
// CSR build: count -> 2-level exclusive scan -> packed atomic fill -> row sort
// ---------------------------------------------------------------------------
__global__ __launch_bounds__(256) void zero_cnt(int* __restrict__ cnt)
{
    int i = blockIdx.x * 256 + threadIdx.x;
    if (i < N_NODES) cnt[i] = 0;
}

__global__ __launch_bounds__(256) void count_keys(
    const int* __restrict__ key, int* __restrict__ cnt)
{
    int i = blockIdx.x * 256 + threadIdx.x;
    if (i < N_EDGES) atomicAdd(&cnt[key[i]], 1);
}

__global__ __launch_bounds__(256) void scan_block_sums(
    const int* __restrict__ cnt, int* __restrict__ bsum)
{
    int i = blockIdx.x * 256 + threadIdx.x;
    int v = (i < N_NODES) ? cnt[i] : 0;
    for (int off = 32; off; off >>= 1) v += __shfl_down(v, off);
    __shared__ int ws_[4];
    if ((threadIdx.x & 63) == 0) ws_[threadIdx.x >> 6] = v;
    __syncthreads();
    if (threadIdx.x == 0) bsum[blockIdx.x] = ws_[0] + ws_[1] + ws_[2] + ws_[3];
}

__global__ __launch_bounds__(512) void scan_partials(
    const int* __restrict__ bsum, int* __restrict__ boff)
{
    int t = threadIdx.x;
    int v = (t < SCAN_B) ? bsum[t] : 0;
    int lane = t & 63, w = t >> 6;
    int x = v;
    for (int off = 1; off < 64; off <<= 1) {
        int y = __shfl_up(x, off);
        if (lane >= off) x += y;
    }
    __shared__ int wsum[8];
    if (lane == 63) wsum[w] = x;
    __syncthreads();
    if (w == 0) {
        int s = (lane < 8) ? wsum[lane] : 0;
        for (int off = 1; off < 8; off <<= 1) {
            int y = __shfl_up(s, off);
            if (lane >= off) s += y;
        }
        if (lane < 8) wsum[lane] = s;
    }
    __syncthreads();
    int wpre = (w == 0) ? 0 : wsum[w - 1];
    if (t < SCAN_B) boff[t] = wpre + x - v;
}

__global__ __launch_bounds__(256) void scan_final(
    const int* __restrict__ cnt, const int* __restrict__ boff,
    int* __restrict__ row_start, int* __restrict__ pos)
{
    int i = blockIdx.x * 256 + threadIdx.x;
    int v = (i < N_NODES) ? cnt[i] : 0;
    int lane = threadIdx.x & 63, w = threadIdx.x >> 6;
    int x = v;
    for (int off = 1; off < 64; off <<= 1) {
        int y = __shfl_up(x, off);
        if (lane >= off) x += y;
    }
    __shared__ int wsum[4];
    if (lane == 63) wsum[w] = x;
    __syncthreads();
    int wpre = 0;
    for (int ww = 0; ww < w; ++ww) wpre += wsum[ww];
    int excl = wpre + x - v;
    int r = boff[blockIdx.x] + excl;
    if (i < N_NODES) { row_start[i] = r; pos[i] = r; }
    if (i == 0) row_start[N_NODES] = N_EDGES;
}

// ---------------------------------------------------------------------------
// XCD-partitioned dst-CSR fill. Baseline fill_dst wrote 198 MB for a 25.6 MB
// csr array (8x partial-line writeback amplification: random 8B stores over a
// 25.6 MB range, lines evicted before their 8 entries arrive). Here blocks
// with blockIdx&7==p (round-robin block->XCD heuristic) handle only dst in
// [p*12500, (p+1)*12500): each XCD's store range is a contiguous ~3.2 MB csr
// slice that FITS its 4 MB L2, so lines accumulate all 8 entries and write
// back once, full. Edge streams are re-read by all 8 partitions (L3 absorbs)
// and loaded nontemporal so they don't evict the resident csr lines.
// ---------------------------------------------------------------------------
__global__ __launch_bounds__(256) void fill_dst_part(
    const int* __restrict__ esrc, const int* __restrict__ edst,
    const float* __restrict__ ew, int* __restrict__ pos,
    int2* __restrict__ csr)
{
    const int part = blockIdx.x & (NPART - 1);
    const int lo = part * PART_N;
    const int hi = lo + PART_N;
    const int pthreads = (FILL_GRID / NPART) * 256;   // 65536 threads/partition
    const int NQUAD = N_EDGES / 4;                    // 800000

    for (int qd = (blockIdx.x >> 3) * 256 + threadIdx.x; qd < NQUAD; qd += pthreads) {
        iv4 d4 = __builtin_nontemporal_load((const iv4*)edst + qd);
        const int i0 = qd * 4;
#define DO_EDGE(DV, IDX) do {                                        \
        int d_ = (DV);                                               \
        if (d_ >= lo && d_ < hi) {                                   \
            int   s_ = __builtin_nontemporal_load(&esrc[IDX]);       \
            float w_ = __builtin_nontemporal_load(&ew[IDX]);         \
            int   q_ = atomicAdd(&pos[d_], 1);                       \
            csr[q_] = make_int2(s_, __float_as_int(0.9f * w_));      \
        } } while (0)
        DO_EDGE(d4.x, i0 + 0);
        DO_EDGE(d4.y, i0 + 1);
        DO_EDGE(d4.z, i0 + 2);
        DO_EDGE(d4.w, i0 + 3);
#undef DO_EDGE
    }
}

// In-row bitonic sort by src (locality only — correctness never depends on
// order). One wave per row; sorts first min(len,64) entries.
__global__ __launch_bounds__(256) void sort_rows(
    const int* __restrict__ row_start, int2* __restrict__ csr)
{
    const int node = blockIdx.x * 4 + (threadIdx.x >> 6);
    const int lane = threadIdx.x & 63;
    const int s0 = row_start[node];
    const int s1 = row_start[node + 1];
    int n = s1 - s0; if (n > 64) n = 64;
    int key = 0x7fffffff;
    int val = 0;
    if (lane < n) { int2 e = csr[s0 + lane]; key = e.x; val = e.y; }
    #pragma unroll
    for (int k = 2; k <= 64; k <<= 1) {
        #pragma unroll
        for (int j = k >> 1; j > 0; j >>= 1) {
            int pk = __shfl_xor(key, j, 64);
            int pv = __shfl_xor(val, j, 64);
            bool lower   = (lane & j) == 0;
            bool asc     = (lane & k) == 0;
            bool takeMin = (lower == asc);
            bool pick    = takeMin ? (pk < key) : (pk > key);
            if (pick) { key = pk; val = pv; }
        }
    }
    if (lane < n) csr[s0 + lane] = make_int2(key, val);
}

// ---------------------------------------------------------------------------
// Pull-based SpMM, bf16 z. One wave per dst node. 8 lanes x 16 B cover one
// z-row (64 bf16): one global_load_dwordx4 gathers 8 edges -> 8 distinct
// 128 B lines per VMEM instr. Unroll 4 => 32 edge-lines in flight per wave.
// Group g = lane>>3 owns edge slot; q = lane&7 owns features 8q..8q+7.
// Row-end reduction: 3 shfl_xor rounds over groups.
// NOTE: macro params named WV/ZV — .x/.y/.z/.w member tokens must NOT
// collide with parameter names (round-5 compile failure).
// ---------------------------------------------------------------------------
template <bool FINAL>
__global__ __launch_bounds__(256) void spmm_kernel(
    const int* __restrict__ row_start, const int2* __restrict__ csr,
    const ushort_t* __restrict__ zin, const ushort_t* __restrict__ ahb,
    void* __restrict__ zout)
{
    const int node = blockIdx.x * 4 + (threadIdx.x >> 6);  // 25000*4 == 100000
    const int lane = threadIdx.x & 63;
    const int g = lane >> 3;    // edge slot 0..7
    const int q = lane & 7;     // feature octet
    const int s0 = __builtin_amdgcn_readfirstlane(row_start[node]);
    const int s1 = __builtin_amdgcn_readfirstlane(row_start[node + 1]);

    float a0=0.f,a1=0.f,a2=0.f,a3=0.f,a4=0.f,a5=0.f,a6=0.f,a7=0.f;
    if (g == 0) {
        uint4 t = *(const uint4*)&ahb[node * 64 + 8 * q];
        a0 = bflo(t.x); a1 = bfhi(t.x); a2 = bflo(t.y); a3 = bfhi(t.y);
        a4 = bflo(t.z); a5 = bfhi(t.z); a6 = bflo(t.w); a7 = bfhi(t.w);
    }

#define FMA8(WV, ZV) do { \
        a0 = fmaf((WV), bflo((ZV).x), a0); a1 = fmaf((WV), bfhi((ZV).x), a1); \
        a2 = fmaf((WV), bflo((ZV).y), a2); a3 = fmaf((WV), bfhi((ZV).y), a3); \
        a4 = fmaf((WV), bflo((ZV).z), a4); a5 = fmaf((WV), bfhi((ZV).z), a5); \
        a6 = fmaf((WV), bflo((ZV).w), a6); a7 = fmaf((WV), bfhi((ZV).w), a7); \
    } while (0)

    int j = s0;
    for (; j + 32 <= s1; j += 32) {
        int2 e0 = csr[j + g];
        int2 e1 = csr[j + 8 + g];
        int2 e2 = csr[j + 16 + g];
        int2 e3 = csr[j + 24 + g];
        uint4 z0 = *(const uint4*)&zin[e0.x * 64 + 8 * q];
        uint4 z1 = *(const uint4*)&zin[e1.x * 64 + 8 * q];
        uint4 z2 = *(const uint4*)&zin[e2.x * 64 + 8 * q];
        uint4 z3 = *(const uint4*)&zin[e3.x * 64 + 8 * q];
        float w0 = __int_as_float(e0.y);
        float w1 = __int_as_float(e1.y);
        float w2 = __int_as_float(e2.y);
        float w3 = __int_as_float(e3.y);
        FMA8(w0, z0);
        FMA8(w1, z1);
        FMA8(w2, z2);
        FMA8(w3, z3);
    }
    for (; j < s1; j += 8) {
        int2 e = make_int2(0, 0);
        int jj = j + g;
        if (jj < s1) e = csr[jj];
        uint4 zt = *(const uint4*)&zin[e.x * 64 + 8 * q];
        float wt = __int_as_float(e.y);
        FMA8(wt, zt);
    }
#undef FMA8

    // reduce the 8 edge-slot groups (lane bits 3,4,5)
    #pragma unroll
    for (int m = 8; m <= 32; m <<= 1) {
        a0 += __shfl_xor(a0, m, 64); a1 += __shfl_xor(a1, m, 64);
        a2 += __shfl_xor(a2, m, 64); a3 += __shfl_xor(a3, m, 64);
        a4 += __shfl_xor(a4, m, 64); a5 += __shfl_xor(a5, m, 64);
        a6 += __shfl_xor(a6, m, 64); a7 += __shfl_xor(a7, m, 64);
    }

    if (g == 0) {
        if (FINAL) {
            float* op = (float*)zout + node * 64 + 8 * q;
            *(float4*)op       = make_float4(a0, a1, a2, a3);
            *(float4*)(op + 4) = make_float4(a4, a5, a6, a7);
        } else {
            uint4 pk;
            pk.x = packbf(a0, a1); pk.y = packbf(a2, a3);
            pk.z = packbf(a4, a5); pk.w = packbf(a6, a7);
            *(uint4*)&((ushort_t*)zout)[node * 64 + 8 * q] = pk;
        }
    }
}

// ---------------------------------------------------------------------------
extern "C" void kernel_launch(void* const* d_in, const int* in_sizes, int n_in,
                              void* d_out, int out_size, void* d_ws, size_t ws_size,
                              hipStream_t stream)
{
    const float* x    = (const float*)d_in[0];
    const int*   esrc = (const int*)d_in[1];
    const int*   edst = (const int*)d_in[2];
    const float* ew   = (const float*)d_in[3];
    const float* W1   = (const float*)d_in[4];
    const float* b1   = (const float*)d_in[5];
    const float* W2   = (const float*)d_in[6];
    const float* b2   = (const float*)d_in[7];
    float* out = (float*)d_out;

    // workspace layout (~65 MB)
    char* p = (char*)d_ws;
    ushort_t* ahb = (ushort_t*)p;  p += (size_t)N_NODES * 64 * 2;   // 12.8M
    ushort_t* hb  = (ushort_t*)p;  p += (size_t)N_NODES * 64 * 2;   // 12.8M (ping-pong buf)
    ushort_t* zB  = (ushort_t*)p;  p += (size_t)N_NODES * 64 * 2;   // 12.8M
    int2*  csr     = (int2*)p;     p += (size_t)N_EDGES * 8;        // 25.6M
    int* cnt       = (int*)p;      p += (size_t)N_NODES * 4;
    int* pos       = (int*)p;      p += (size_t)N_NODES * 4;
    int* row_start = (int*)p;      p += (size_t)(N_NODES + 1) * 4;
    int* bsum      = (int*)p;      p += (size_t)SCAN_B * 4;
    int* boff      = (int*)p;      p += (size_t)SCAN_B * 4;

    const int EB = (N_EDGES + 255) / 256;

    hipLaunchKernelGGL(mlp_kernel, dim3(N_NODES / 32), dim3(256), 0, stream,
                       x, W1, b1, W2, b2, hb, ahb);

    // counting sort by dst, packed payload, then in-row sort by src
    hipLaunchKernelGGL(zero_cnt, dim3(SCAN_B), dim3(256), 0, stream, cnt);
    hipLaunchKernelGGL(count_keys, dim3(EB), dim3(256), 0, stream, edst, cnt);
    hipLaunchKernelGGL(scan_block_sums, dim3(SCAN_B), dim3(256), 0, stream, cnt, bsum);
    hipLaunchKernelGGL(scan_partials, dim3(1), dim3(512), 0, stream, bsum, boff);
    hipLaunchKernelGGL(scan_final, dim3(SCAN_B), dim3(256), 0, stream,
                       cnt, boff, row_start, pos);
    hipLaunchKernelGGL(fill_dst_part, dim3(FILL_GRID), dim3(256), 0, stream,
                       esrc, edst, ew, pos, csr);
    hipLaunchKernelGGL(sort_rows, dim3(N_NODES / 4), dim3(256), 0, stream,
                       row_start, csr);

    // propagation: strict alternation. it even: ->zB, it odd: ->hb.
    // it=0: hb->zB; ... it=8: hb->zB; final (it=9): zB->out(fp32).
    const ushort_t* zi = hb;
    for (int it = 0; it < K_ITERS - 1; ++it) {
        ushort_t* zo = (it % 2 == 0) ? zB : hb;
        hipLaunchKernelGGL((spmm_kernel<false>), dim3(N_NODES / 4), dim3(256), 0, stream,
                           row_start, csr, zi, ahb, (void*)zo);
        zi = zo;
    }
    hipLaunchKernelGGL((spmm_kernel<true>), dim3(N_NODES / 4), dim3(256), 0, stream,
                       row_start, csr, zi, ahb, (void*)out);
}

// Round 3
// 1317.087 us; speedup vs baseline: 1.0919x; 1.0592x over previous
//
#include <hip/hip_runtime.h>

#define N_NODES 100000
#define N_EDGES 3200000
#define IN_F 500
#define HID 64
#define OUT_F 64
#define ALPHA 0.1f
#define K_ITERS 10
#define SCAN_B ((N_NODES + 255) / 256)   // 391

#define NPART 8                 // XCD count (m09)
#define PART_N (N_NODES / NPART)         // 12500
#define FILL_GRID 2048          // 8 blocks/CU x 256 CU -> fully resident

#define KPAD 512                // IN_F padded to MFMA K-step multiple

typedef unsigned short ushort_t;
typedef unsigned int uint_t;
typedef int iv4 __attribute__((ext_vector_type(4)));   // native vec: OK for nontemporal builtins
typedef __attribute__((ext_vector_type(8))) short bf16x8;   // MFMA A/B frag (4 VGPR)
typedef __attribute__((ext_vector_type(4))) float f32x4;    // MFMA C/D frag

__device__ __forceinline__ float bf2f(ushort_t v) {
    union { uint_t u; float f; } c; c.u = ((uint_t)v) << 16; return c.f;
}
__device__ __forceinline__ ushort_t f2b(float f) {
    union { float f; uint_t u; } c; c.f = f;
    uint_t u = c.u + 0x7fffu + ((c.u >> 16) & 1u);   // round-to-nearest-even
    return (ushort_t)(u >> 16);
}
__device__ __forceinline__ float bflo(uint_t u) {
    union { uint_t u; float f; } c; c.u = u << 16; return c.f;
}
__device__ __forceinline__ float bfhi(uint_t u) {
    union { uint_t u; float f; } c; c.u = u & 0xffff0000u; return c.f;
}
__device__ __forceinline__ uint_t packbf(float a, float b) {
    return (uint_t)f2b(a) | ((uint_t)f2b(b) << 16);
}
__device__ __forceinline__ bf16x8 pack8(float4 a, float4 b) {
    bf16x8 r;
    r[0] = (short)f2b(a.x); r[1] = (short)f2b(a.y);
    r[2] = (short)f2b(a.z); r[3] = (short)f2b(a.w);
    r[4] = (short)f2b(b.x); r[5] = (short)f2b(b.y);
    r[6] = (short)f2b(b.z); r[7] = (short)f2b(b.w);
    return r;
}

// ---------------------------------------------------------------------------
// Weight prep: W1[500x64] -> w1t bf16 [64][512] (transposed, K zero-padded),
// W2[64x64] -> w2t bf16 [64][64] (transposed). Fragment-friendly: B-frag for
// mfma_16x16x32 is lane l -> B[k=(l>>4)*8+e][col=l&15], so storing [col][k]
// makes each frag one contiguous 16 B load. Tiny one-shot kernel.
// ---------------------------------------------------------------------------
__global__ __launch_bounds__(256) void prep_weights(
    const float* __restrict__ W1, const float* __restrict__ W2,
    ushort_t* __restrict__ w1t, ushort_t* __restrict__ w2t)
{
    int i = blockIdx.x * 256 + threadIdx.x;
    if (i < 64 * KPAD) {
        int c = i >> 9, k = i & (KPAD - 1);
        float v = (k < IN_F) ? W1[k * HID + c] : 0.f;
        w1t[c * KPAD + k] = f2b(v);
    } else {
        int j = i - 64 * KPAD;
        if (j < 64 * 64) {
            int c = j >> 6, k = j & 63;
            w2t[c * 64 + k] = f2b(W2[k * OUT_F + c]);
        }
    }
}

// ---------------------------------------------------------------------------
// MFMA MLP: v = relu(x@W1+b1)@W2+b2 ; hb = bf16(v), ahb = bf16(ALPHA*v).
// Block = 256 (4 waves), 64 rows; wave w owns rows w*16..+15 (one M-tile).
// Layer 1: 4 col-tiles x 16 k-steps of mfma_f32_16x16x32_bf16. A-frags load
// straight from global x (lane l: 32 B of row l&15 at k=(l>>4)*8) + in-reg
// fp32->bf16 RNE; B-frags from L2-hot w1t. Layer 2 re-fragments the hidden
// tile through per-wave LDS (C/D layout != A layout), then 8 MFMAs vs w2t.
// Memory floor ~226 MB => ~36 us; old VALU version measured 241 us.
// ---------------------------------------------------------------------------
__global__ __launch_bounds__(256) void mlp_mfma(
    const float* __restrict__ x, const ushort_t* __restrict__ w1t,
    const float* __restrict__ b1, const ushort_t* __restrict__ w2t,
    const float* __restrict__ b2, ushort_t* __restrict__ hb,
    ushort_t* __restrict__ ahb)
{
    __shared__ ushort_t hs[4][16][64];   // per-wave hidden tile, 8 KB total

    const int lane = threadIdx.x & 63;
    const int wid  = threadIdx.x >> 6;
    const int r16  = lane & 15;          // A-row / B-col within tile
    const int kg   = lane >> 4;          // k-group 0..3
    const int rowbase = blockIdx.x * 64 + wid * 16;

    int arow  = rowbase + r16;
    int lrow  = (arow < N_NODES) ? arow : (N_NODES - 1);   // clamp loads only
    const float* xr = x + (long)lrow * IN_F;

    f32x4 acc[4];
    #pragma unroll
    for (int t = 0; t < 4; ++t) acc[t] = (f32x4){0.f, 0.f, 0.f, 0.f};

    for (int ks = 0; ks < KPAD / 32; ++ks) {
        const int k0 = ks * 32 + kg * 8;
        bf16x8 af;
        if (k0 + 8 <= IN_F) {
            float4 xa = *(const float4*)(xr + k0);
            float4 xb = *(const float4*)(xr + k0 + 4);
            af = pack8(xa, xb);
        } else {
            #pragma unroll
            for (int i = 0; i < 8; ++i) {
                float v = (k0 + i < IN_F) ? xr[k0 + i] : 0.f;
                af[i] = (short)f2b(v);
            }
        }
        #pragma unroll
        for (int t = 0; t < 4; ++t) {
            bf16x8 bfw = *(const bf16x8*)&w1t[(t * 16 + r16) * KPAD + k0];
            acc[t] = __builtin_amdgcn_mfma_f32_16x16x32_bf16(af, bfw, acc[t], 0, 0, 0);
        }
    }

    // bias + relu, stash hidden tile (C/D layout: row=kg*4+r, col=t*16+r16)
    #pragma unroll
    for (int t = 0; t < 4; ++t) {
        float bb = b1[t * 16 + r16];
        #pragma unroll
        for (int r = 0; r < 4; ++r) {
            float h = fmaxf(acc[t][r] + bb, 0.f);
            hs[wid][kg * 4 + r][t * 16 + r16] = f2b(h);
        }
    }
    __syncthreads();   // cross-lane LDS visibility (cheap: once per block)

    f32x4 acc2[4];
    #pragma unroll
    for (int t = 0; t < 4; ++t) acc2[t] = (f32x4){0.f, 0.f, 0.f, 0.f};

    #pragma unroll
    for (int ks = 0; ks < 2; ++ks) {
        bf16x8 ha = *(const bf16x8*)&hs[wid][r16][ks * 32 + kg * 8];
        #pragma unroll
        for (int t = 0; t < 4; ++t) {
            bf16x8 wb = *(const bf16x8*)&w2t[(t * 16 + r16) * 64 + ks * 32 + kg * 8];
            acc2[t] = __builtin_amdgcn_mfma_f32_16x16x32_bf16(ha, wb, acc2[t], 0, 0, 0);
        }
    }

    #pragma unroll
    for (int t = 0; t < 4; ++t) {
        float bb = b2[t * 16 + r16];
        #pragma unroll
        for (int r = 0; r < 4; ++r) {
            int orow = rowbase + kg * 4 + r;
            if (orow < N_NODES) {
                float v = acc2[t][r] + bb;
                hb[orow * 64 + t * 16 + r16]  = f2b(v);
                ahb[orow * 64 + t * 16 + r16] = f2b(ALPHA * v);
            }
        }
    }
}

// ---------------------------------------------------------------------------
// CSR build: count -> 2-level exclusive scan -> packed atomic fill -> row sort
// ---------------------------------------------------------------------------
__global__ __launch_bounds__(256) void zero_cnt(int* __restrict__ cnt)
{
    int i = blockIdx.x * 256 + threadIdx.x;
    if (i < N_NODES) cnt[i] = 0;
}

__global__ __launch_bounds__(256) void count_keys(
    const int* __restrict__ key, int* __restrict__ cnt)
{
    int i = blockIdx.x * 256 + threadIdx.x;
    if (i < N_EDGES) atomicAdd(&cnt[key[i]], 1);
}

__global__ __launch_bounds__(256) void scan_block_sums(
    const int* __restrict__ cnt, int* __restrict__ bsum)
{
    int i = blockIdx.x * 256 + threadIdx.x;
    int v = (i < N_NODES) ? cnt[i] : 0;
    for (int off = 32; off; off >>= 1) v += __shfl_down(v, off);
    __shared__ int ws_[4];
    if ((threadIdx.x & 63) == 0) ws_[threadIdx.x >> 6] = v;
    __syncthreads();
    if (threadIdx.x == 0) bsum[blockIdx.x] = ws_[0] + ws_[1] + ws_[2] + ws_[3];
}

__global__ __launch_bounds__(512) void scan_partials(
    const int* __restrict__ bsum, int* __restrict__ boff)
{
    int t = threadIdx.x;
    int v = (t < SCAN_B) ? bsum[t] : 0;
    int lane = t & 63, w = t >> 6;
    int x = v;
    for (int off = 1; off < 64; off <<= 1) {
        int y = __shfl_up(x, off);
        if (lane >= off) x += y;
    }
    __shared__ int wsum[8];
    if (lane == 63) wsum[w] = x;
    __syncthreads();
    if (w == 0) {
        int s = (lane < 8) ? wsum[lane] : 0;
        for (int off = 1; off < 8; off <<= 1) {
            int y = __shfl_up(s, off);
            if (lane >= off) s += y;
        }
        if (lane < 8) wsum[lane] = s;
    }
    __syncthreads();
    int wpre = (w == 0) ? 0 : wsum[w - 1];
    if (t < SCAN_B) boff[t] = wpre + x - v;
}

__global__ __launch_bounds__(256) void scan_final(
    const int* __restrict__ cnt, const int* __restrict__ boff,
    int* __restrict__ row_start, int* __restrict__ pos)
{
    int i = blockIdx.x * 256 + threadIdx.x;
    int v = (i < N_NODES) ? cnt[i] : 0;
    int lane = threadIdx.x & 63, w = threadIdx.x >> 6;
    int x = v;
    for (int off = 1; off < 64; off <<= 1) {
        int y = __shfl_up(x, off);
        if (lane >= off) x += y;
    }
    __shared__ int wsum[4];
    if (lane == 63) wsum[w] = x;
    __syncthreads();
    int wpre = 0;
    for (int ww = 0; ww < w; ++ww) wpre += wsum[ww];
    int excl = wpre + x - v;
    int r = boff[blockIdx.x] + excl;
    if (i < N_NODES) { row_start[i] = r; pos[i] = r; }
    if (i == 0) row_start[N_NODES] = N_EDGES;
}

// ---------------------------------------------------------------------------
// XCD-partitioned dst-CSR fill (round-1 win: WRITE_SIZE 198 MB -> near-ideal).
// Blocks with blockIdx&7==p handle only dst in [p*12500,(p+1)*12500): each
// XCD's store range is a contiguous ~3.2 MB csr slice that fits its 4 MB L2,
// so lines accumulate all 8 entries and write back once, full. Edge streams
// re-read 8x (L3 absorbs), nontemporal so they don't evict resident csr lines.
// ---------------------------------------------------------------------------
__global__ __launch_bounds__(256) void fill_dst_part(
    const int* __restrict__ esrc, const int* __restrict__ edst,
    const float* __restrict__ ew, int* __restrict__ pos,
    int2* __restrict__ csr)
{
    const int part = blockIdx.x & (NPART - 1);
    const int lo = part * PART_N;
    const int hi = lo + PART_N;
    const int pthreads = (FILL_GRID / NPART) * 256;   // 65536 threads/partition
    const int NQUAD = N_EDGES / 4;                    // 800000

    for (int qd = (blockIdx.x >> 3) * 256 + threadIdx.x; qd < NQUAD; qd += pthreads) {
        iv4 d4 = __builtin_nontemporal_load((const iv4*)edst + qd);
        const int i0 = qd * 4;
#define DO_EDGE(DV, IDX) do {                                        \
        int d_ = (DV);                                               \
        if (d_ >= lo && d_ < hi) {                                   \
            int   s_ = __builtin_nontemporal_load(&esrc[IDX]);       \
            float w_ = __builtin_nontemporal_load(&ew[IDX]);         \
            int   q_ = atomicAdd(&pos[d_], 1);                       \
            csr[q_] = make_int2(s_, __float_as_int(0.9f * w_));      \
        } } while (0)
        DO_EDGE(d4.x, i0 + 0);
        DO_EDGE(d4.y, i0 + 1);
        DO_EDGE(d4.z, i0 + 2);
        DO_EDGE(d4.w, i0 + 3);
#undef DO_EDGE
    }
}

// In-row bitonic sort by src (locality only — correctness never depends on
// order). One wave per row; sorts first min(len,64) entries.
__global__ __launch_bounds__(256) void sort_rows(
    const int* __restrict__ row_start, int2* __restrict__ csr)
{
    const int node = blockIdx.x * 4 + (threadIdx.x >> 6);
    const int lane = threadIdx.x & 63;
    const int s0 = row_start[node];
    const int s1 = row_start[node + 1];
    int n = s1 - s0; if (n > 64) n = 64;
    int key = 0x7fffffff;
    int val = 0;
    if (lane < n) { int2 e = csr[s0 + lane]; key = e.x; val = e.y; }
    #pragma unroll
    for (int k = 2; k <= 64; k <<= 1) {
        #pragma unroll
        for (int j = k >> 1; j > 0; j >>= 1) {
            int pk = __shfl_xor(key, j, 64);
            int pv = __shfl_xor(val, j, 64);
            bool lower   = (lane & j) == 0;
            bool asc     = (lane & k) == 0;
            bool takeMin = (lower == asc);
            bool pick    = takeMin ? (pk < key) : (pk > key);
            if (pick) { key = pk; val = pv; }
        }
    }
    if (lane < n) csr[s0 + lane] = make_int2(key, val);
}

// ---------------------------------------------------------------------------
// Pull-based SpMM, bf16 z. One wave per dst node. 8 lanes x 16 B cover one
// z-row (64 bf16): one global_load_dwordx4 gathers 8 edges -> 8 distinct
// 128 B lines per VMEM instr. Unroll 4 => 32 edge-lines in flight per wave.
// Group g = lane>>3 owns edge slot; q = lane&7 owns features 8q..8q+7.
// Row-end reduction: 3 shfl_xor rounds over groups.
// NOTE: macro params named WV/ZV — .x/.y/.z/.w member tokens must NOT
// collide with parameter names (round-5 compile failure).
// ---------------------------------------------------------------------------
template <bool FINAL>
__global__ __launch_bounds__(256) void spmm_kernel(
    const int* __restrict__ row_start, const int2* __restrict__ csr,
    const ushort_t* __restrict__ zin, const ushort_t* __restrict__ ahb,
    void* __restrict__ zout)
{
    const int node = blockIdx.x * 4 + (threadIdx.x >> 6);  // 25000*4 == 100000
    const int lane = threadIdx.x & 63;
    const int g = lane >> 3;    // edge slot 0..7
    const int q = lane & 7;     // feature octet
    const int s0 = __builtin_amdgcn_readfirstlane(row_start[node]);
    const int s1 = __builtin_amdgcn_readfirstlane(row_start[node + 1]);

    float a0=0.f,a1=0.f,a2=0.f,a3=0.f,a4=0.f,a5=0.f,a6=0.f,a7=0.f;
    if (g == 0) {
        uint4 t = *(const uint4*)&ahb[node * 64 + 8 * q];
        a0 = bflo(t.x); a1 = bfhi(t.x); a2 = bflo(t.y); a3 = bfhi(t.y);
        a4 = bflo(t.z); a5 = bfhi(t.z); a6 = bflo(t.w); a7 = bfhi(t.w);
    }

#define FMA8(WV, ZV) do { \
        a0 = fmaf((WV), bflo((ZV).x), a0); a1 = fmaf((WV), bfhi((ZV).x), a1); \
        a2 = fmaf((WV), bflo((ZV).y), a2); a3 = fmaf((WV), bfhi((ZV).y), a3); \
        a4 = fmaf((WV), bflo((ZV).z), a4); a5 = fmaf((WV), bfhi((ZV).z), a5); \
        a6 = fmaf((WV), bflo((ZV).w), a6); a7 = fmaf((WV), bfhi((ZV).w), a7); \
    } while (0)

    int j = s0;
    for (; j + 32 <= s1; j += 32) {
        int2 e0 = csr[j + g];
        int2 e1 = csr[j + 8 + g];
        int2 e2 = csr[j + 16 + g];
        int2 e3 = csr[j + 24 + g];
        uint4 z0 = *(const uint4*)&zin[e0.x * 64 + 8 * q];
        uint4 z1 = *(const uint4*)&zin[e1.x * 64 + 8 * q];
        uint4 z2 = *(const uint4*)&zin[e2.x * 64 + 8 * q];
        uint4 z3 = *(const uint4*)&zin[e3.x * 64 + 8 * q];
        float w0 = __int_as_float(e0.y);
        float w1 = __int_as_float(e1.y);
        float w2 = __int_as_float(e2.y);
        float w3 = __int_as_float(e3.y);
        FMA8(w0, z0);
        FMA8(w1, z1);
        FMA8(w2, z2);
        FMA8(w3, z3);
    }
    for (; j < s1; j += 8) {
        int2 e = make_int2(0, 0);
        int jj = j + g;
        if (jj < s1) e = csr[jj];
        uint4 zt = *(const uint4*)&zin[e.x * 64 + 8 * q];
        float wt = __int_as_float(e.y);
        FMA8(wt, zt);
    }
#undef FMA8

    // reduce the 8 edge-slot groups (lane bits 3,4,5)
    #pragma unroll
    for (int m = 8; m <= 32; m <<= 1) {
        a0 += __shfl_xor(a0, m, 64); a1 += __shfl_xor(a1, m, 64);
        a2 += __shfl_xor(a2, m, 64); a3 += __shfl_xor(a3, m, 64);
        a4 += __shfl_xor(a4, m, 64); a5 += __shfl_xor(a5, m, 64);
        a6 += __shfl_xor(a6, m, 64); a7 += __shfl_xor(a7, m, 64);
    }

    if (g == 0) {
        if (FINAL) {
            float* op = (float*)zout + node * 64 + 8 * q;
            *(float4*)op       = make_float4(a0, a1, a2, a3);
            *(float4*)(op + 4) = make_float4(a4, a5, a6, a7);
        } else {
            uint4 pk;
            pk.x = packbf(a0, a1); pk.y = packbf(a2, a3);
            pk.z = packbf(a4, a5); pk.w = packbf(a6, a7);
            *(uint4*)&((ushort_t*)zout)[node * 64 + 8 * q] = pk;
        }
    }
}

// ---------------------------------------------------------------------------
extern "C" void kernel_launch(void* const* d_in, const int* in_sizes, int n_in,
                              void* d_out, int out_size, void* d_ws, size_t ws_size,
                              hipStream_t stream)
{
    const float* x    = (const float*)d_in[0];
    const int*   esrc = (const int*)d_in[1];
    const int*   edst = (const int*)d_in[2];
    const float* ew   = (const float*)d_in[3];
    const float* W1   = (const float*)d_in[4];
    const float* b1   = (const float*)d_in[5];
    const float* W2   = (const float*)d_in[6];
    const float* b2   = (const float*)d_in[7];
    float* out = (float*)d_out;

    // workspace layout (~65 MB)
    char* p = (char*)d_ws;
    ushort_t* ahb = (ushort_t*)p;  p += (size_t)N_NODES * 64 * 2;   // 12.8M
    ushort_t* hb  = (ushort_t*)p;  p += (size_t)N_NODES * 64 * 2;   // 12.8M (ping-pong buf)
    ushort_t* zB  = (ushort_t*)p;  p += (size_t)N_NODES * 64 * 2;   // 12.8M
    int2*  csr     = (int2*)p;     p += (size_t)N_EDGES * 8;        // 25.6M
    int* cnt       = (int*)p;      p += (size_t)N_NODES * 4;
    int* pos       = (int*)p;      p += (size_t)N_NODES * 4;
    int* row_start = (int*)p;      p += (size_t)(N_NODES + 1) * 4;
    int* bsum      = (int*)p;      p += (size_t)SCAN_B * 4;
    int* boff      = (int*)p;      p += (size_t)SCAN_B * 4;
    ushort_t* w1t  = (ushort_t*)p; p += (size_t)64 * KPAD * 2;      // 64 KB
    ushort_t* w2t  = (ushort_t*)p; p += (size_t)64 * 64 * 2;        // 8 KB

    const int EB = (N_EDGES + 255) / 256;

    hipLaunchKernelGGL(prep_weights, dim3((64 * KPAD + 64 * 64 + 255) / 256),
                       dim3(256), 0, stream, W1, W2, w1t, w2t);
    hipLaunchKernelGGL(mlp_mfma, dim3((N_NODES + 63) / 64), dim3(256), 0, stream,
                       x, w1t, b1, w2t, b2, hb, ahb);

    // counting sort by dst, packed payload, then in-row sort by src
    hipLaunchKernelGGL(zero_cnt, dim3(SCAN_B), dim3(256), 0, stream, cnt);
    hipLaunchKernelGGL(count_keys, dim3(EB), dim3(256), 0, stream, edst, cnt);
    hipLaunchKernelGGL(scan_block_sums, dim3(SCAN_B), dim3(256), 0, stream, cnt, bsum);
    hipLaunchKernelGGL(scan_partials, dim3(1), dim3(512), 0, stream, bsum, boff);
    hipLaunchKernelGGL(scan_final, dim3(SCAN_B), dim3(256), 0, stream,
                       cnt, boff, row_start, pos);
    hipLaunchKernelGGL(fill_dst_part, dim3(FILL_GRID), dim3(256), 0, stream,
                       esrc, edst, ew, pos, csr);
    hipLaunchKernelGGL(sort_rows, dim3(N_NODES / 4), dim3(256), 0, stream,
                       row_start, csr);

    // propagation: strict alternation. it even: ->zB, it odd: ->hb.
    // it=0: hb->zB; ... it=8: hb->zB; final (it=9): zB->out(fp32).
    const ushort_t* zi = hb;
    for (int it = 0; it < K_ITERS - 1; ++it) {
        ushort_t* zo = (it % 2 == 0) ? zB : hb;
        hipLaunchKernelGGL((spmm_kernel<false>), dim3(N_NODES / 4), dim3(256), 0, stream,
                           row_start, csr, zi, ahb, (void*)zo);
        zi = zo;
    }
    hipLaunchKernelGGL((spmm_kernel<true>), dim3(N_NODES / 4), dim3(256), 0, stream,
                       row_start, csr, zi, ahb, (void*)out);
}

// Round 4
// 1315.557 us; speedup vs baseline: 1.0932x; 1.0012x over previous
//
#include <hip/hip_runtime.h>

#define N_NODES 100000
#define N_EDGES 3200000
#define IN_F 500
#define HID 64
#define OUT_F 64
#define ALPHA 0.1f
#define K_ITERS 10
#define SCAN_B ((N_NODES + 255) / 256)   // 391

#define NPART 8                          // XCD count (m09)
#define PART_N (N_NODES / NPART)         // 12500
#define FILL_GRID 2048                   // 8 blocks/CU x 256 CU

#define SPLIT_CHUNK 2560                 // edges per block in split_edges
#define SPLIT_ROUNDS 10                  // 2560 / 256
#define SPLIT_GRID (N_EDGES / SPLIT_CHUNK)   // 1250 exactly

#define KPAD 512                // IN_F padded to MFMA K-step multiple

typedef unsigned short ushort_t;
typedef unsigned int uint_t;
typedef __attribute__((ext_vector_type(8))) short bf16x8;   // MFMA A/B frag (4 VGPR)
typedef __attribute__((ext_vector_type(4))) float f32x4;    // MFMA C/D frag

__device__ __forceinline__ float bf2f(ushort_t v) {
    union { uint_t u; float f; } c; c.u = ((uint_t)v) << 16; return c.f;
}
__device__ __forceinline__ ushort_t f2b(float f) {
    union { float f; uint_t u; } c; c.f = f;
    uint_t u = c.u + 0x7fffu + ((c.u >> 16) & 1u);   // round-to-nearest-even
    return (ushort_t)(u >> 16);
}
__device__ __forceinline__ float bflo(uint_t u) {
    union { uint_t u; float f; } c; c.u = u << 16; return c.f;
}
__device__ __forceinline__ float bfhi(uint_t u) {
    union { uint_t u; float f; } c; c.u = u & 0xffff0000u; return c.f;
}
__device__ __forceinline__ uint_t packbf(float a, float b) {
    return (uint_t)f2b(a) | ((uint_t)f2b(b) << 16);
}
__device__ __forceinline__ bf16x8 pack8(float4 a, float4 b) {
    bf16x8 r;
    r[0] = (short)f2b(a.x); r[1] = (short)f2b(a.y);
    r[2] = (short)f2b(a.z); r[3] = (short)f2b(a.w);
    r[4] = (short)f2b(b.x); r[5] = (short)f2b(b.y);
    r[6] = (short)f2b(b.z); r[7] = (short)f2b(b.w);
    return r;
}

// ---------------------------------------------------------------------------
// Weight prep: W1[500x64] -> w1t bf16 [64][512] (transposed, K zero-padded),
// W2[64x64] -> w2t bf16 [64][64] (transposed). B-frag for mfma_16x16x32 is
// lane l -> B[k=(l>>4)*8+e][col=l&15]; storing [col][k] makes each frag one
// contiguous 16 B load. Tiny one-shot kernel.
// ---------------------------------------------------------------------------
__global__ __launch_bounds__(256) void prep_weights(
    const float* __restrict__ W1, const float* __restrict__ W2,
    ushort_t* __restrict__ w1t, ushort_t* __restrict__ w2t)
{
    int i = blockIdx.x * 256 + threadIdx.x;
    if (i < 64 * KPAD) {
        int c = i >> 9, k = i & (KPAD - 1);
        float v = (k < IN_F) ? W1[k * HID + c] : 0.f;
        w1t[c * KPAD + k] = f2b(v);
    } else {
        int j = i - 64 * KPAD;
        if (j < 64 * 64) {
            int c = j >> 6, k = j & 63;
            w2t[c * 64 + k] = f2b(W2[k * OUT_F + c]);
        }
    }
}

// ---------------------------------------------------------------------------
// MFMA MLP: v = relu(x@W1+b1)@W2+b2 ; hb = bf16(v), ahb = bf16(ALPHA*v).
// Block = 256 (4 waves), 64 rows; wave w owns rows w*16..+15 (one M-tile).
// ---------------------------------------------------------------------------
__global__ __launch_bounds__(256) void mlp_mfma(
    const float* __restrict__ x, const ushort_t* __restrict__ w1t,
    const float* __restrict__ b1, const ushort_t* __restrict__ w2t,
    const float* __restrict__ b2, ushort_t* __restrict__ hb,
    ushort_t* __restrict__ ahb)
{
    __shared__ ushort_t hs[4][16][64];   // per-wave hidden tile, 8 KB total

    const int lane = threadIdx.x & 63;
    const int wid  = threadIdx.x >> 6;
    const int r16  = lane & 15;          // A-row / B-col within tile
    const int kg   = lane >> 4;          // k-group 0..3
    const int rowbase = blockIdx.x * 64 + wid * 16;

    int arow  = rowbase + r16;
    int lrow  = (arow < N_NODES) ? arow : (N_NODES - 1);   // clamp loads only
    const float* xr = x + (long)lrow * IN_F;

    f32x4 acc[4];
    #pragma unroll
    for (int t = 0; t < 4; ++t) acc[t] = (f32x4){0.f, 0.f, 0.f, 0.f};

    for (int ks = 0; ks < KPAD / 32; ++ks) {
        const int k0 = ks * 32 + kg * 8;
        bf16x8 af;
        if (k0 + 8 <= IN_F) {
            float4 xa = *(const float4*)(xr + k0);
            float4 xb = *(const float4*)(xr + k0 + 4);
            af = pack8(xa, xb);
        } else {
            #pragma unroll
            for (int i = 0; i < 8; ++i) {
                float v = (k0 + i < IN_F) ? xr[k0 + i] : 0.f;
                af[i] = (short)f2b(v);
            }
        }
        #pragma unroll
        for (int t = 0; t < 4; ++t) {
            bf16x8 bfw = *(const bf16x8*)&w1t[(t * 16 + r16) * KPAD + k0];
            acc[t] = __builtin_amdgcn_mfma_f32_16x16x32_bf16(af, bfw, acc[t], 0, 0, 0);
        }
    }

    // bias + relu, stash hidden tile (C/D layout: row=kg*4+r, col=t*16+r16)
    #pragma unroll
    for (int t = 0; t < 4; ++t) {
        float bb = b1[t * 16 + r16];
        #pragma unroll
        for (int r = 0; r < 4; ++r) {
            float h = fmaxf(acc[t][r] + bb, 0.f);
            hs[wid][kg * 4 + r][t * 16 + r16] = f2b(h);
        }
    }
    __syncthreads();

    f32x4 acc2[4];
    #pragma unroll
    for (int t = 0; t < 4; ++t) acc2[t] = (f32x4){0.f, 0.f, 0.f, 0.f};

    #pragma unroll
    for (int ks = 0; ks < 2; ++ks) {
        bf16x8 ha = *(const bf16x8*)&hs[wid][r16][ks * 32 + kg * 8];
        #pragma unroll
        for (int t = 0; t < 4; ++t) {
            bf16x8 wb = *(const bf16x8*)&w2t[(t * 16 + r16) * 64 + ks * 32 + kg * 8];
            acc2[t] = __builtin_amdgcn_mfma_f32_16x16x32_bf16(ha, wb, acc2[t], 0, 0, 0);
        }
    }

    #pragma unroll
    for (int t = 0; t < 4; ++t) {
        float bb = b2[t * 16 + r16];
        #pragma unroll
        for (int r = 0; r < 4; ++r) {
            int orow = rowbase + kg * 4 + r;
            if (orow < N_NODES) {
                float v = acc2[t][r] + bb;
                hb[orow * 64 + t * 16 + r16]  = f2b(v);
                ahb[orow * 64 + t * 16 + r16] = f2b(ALPHA * v);
            }
        }
    }
}

// ---------------------------------------------------------------------------
// CSR build: count -> 2-level exclusive scan -> partition split -> in-slice
// scatter -> row sort
// ---------------------------------------------------------------------------
__global__ __launch_bounds__(256) void zero_cnt(int* __restrict__ cnt)
{
    int i = blockIdx.x * 256 + threadIdx.x;
    if (i < N_NODES) cnt[i] = 0;
}

__global__ __launch_bounds__(256) void count_keys(
    const int* __restrict__ key, int* __restrict__ cnt)
{
    int i = blockIdx.x * 256 + threadIdx.x;
    if (i < N_EDGES) atomicAdd(&cnt[key[i]], 1);
}

__global__ __launch_bounds__(256) void scan_block_sums(
    const int* __restrict__ cnt, int* __restrict__ bsum)
{
    int i = blockIdx.x * 256 + threadIdx.x;
    int v = (i < N_NODES) ? cnt[i] : 0;
    for (int off = 32; off; off >>= 1) v += __shfl_down(v, off);
    __shared__ int ws_[4];
    if ((threadIdx.x & 63) == 0) ws_[threadIdx.x >> 6] = v;
    __syncthreads();
    if (threadIdx.x == 0) bsum[blockIdx.x] = ws_[0] + ws_[1] + ws_[2] + ws_[3];
}

__global__ __launch_bounds__(512) void scan_partials(
    const int* __restrict__ bsum, int* __restrict__ boff)
{
    int t = threadIdx.x;
    int v = (t < SCAN_B) ? bsum[t] : 0;
    int lane = t & 63, w = t >> 6;
    int x = v;
    for (int off = 1; off < 64; off <<= 1) {
        int y = __shfl_up(x, off);
        if (lane >= off) x += y;
    }
    __shared__ int wsum[8];
    if (lane == 63) wsum[w] = x;
    __syncthreads();
    if (w == 0) {
        int s = (lane < 8) ? wsum[lane] : 0;
        for (int off = 1; off < 8; off <<= 1) {
            int y = __shfl_up(s, off);
            if (lane >= off) s += y;
        }
        if (lane < 8) wsum[lane] = s;
    }
    __syncthreads();
    int wpre = (w == 0) ? 0 : wsum[w - 1];
    if (t < SCAN_B) boff[t] = wpre + x - v;
}

// also seeds pcur[p] = row_start[p*PART_N] (exact partition bases for split)
__global__ __launch_bounds__(256) void scan_final(
    const int* __restrict__ cnt, const int* __restrict__ boff,
    int* __restrict__ row_start, int* __restrict__ pos,
    int* __restrict__ pcur)
{
    int i = blockIdx.x * 256 + threadIdx.x;
    int v = (i < N_NODES) ? cnt[i] : 0;
    int lane = threadIdx.x & 63, w = threadIdx.x >> 6;
    int x = v;
    for (int off = 1; off < 64; off <<= 1) {
        int y = __shfl_up(x, off);
        if (lane >= off) x += y;
    }
    __shared__ int wsum[4];
    if (lane == 63) wsum[w] = x;
    __syncthreads();
    int wpre = 0;
    for (int ww = 0; ww < w; ++ww) wpre += wsum[ww];
    int excl = wpre + x - v;
    int r = boff[blockIdx.x] + excl;
    if (i < N_NODES) {
        row_start[i] = r; pos[i] = r;
        if ((i % PART_N) == 0) pcur[i / PART_N] = r;
    }
    if (i == 0) row_start[N_NODES] = N_EDGES;
}

// ---------------------------------------------------------------------------
// Pass A: partition split. Each block owns 2560 consecutive edges.
// Sweep 1 counts per-partition via wave ballots (lane p accumulates part p);
// block reserves its regions with 8 global atomics (10K total — no hot-spot).
// Sweep 2 writes edges compacted into partition-grouped sbuf: every store is
// part of a dense per-block run -> full-line writes by construction.
// Entry: (dst_local<<17 | src, w)  [dst_local<12500 fits 14b, src<100000 17b].
// sbuf ALIASES ahb+hb (25.6 MB) — legal: split+fill_b run before mlp_mfma.
// ---------------------------------------------------------------------------
__global__ __launch_bounds__(256) void split_edges(
    const int* __restrict__ esrc, const int* __restrict__ edst,
    const float* __restrict__ ew, int* __restrict__ pcur,
    int2* __restrict__ sbuf)
{
    __shared__ int lbase[NPART];
    const int tid  = threadIdx.x;
    const int lane = tid & 63;
    const int base = blockIdx.x * SPLIT_CHUNK;
    const unsigned long long below = (lane == 63) ? ~0ull >> 1
                                                  : (1ull << lane) - 1ull;

    if (tid < NPART) lbase[tid] = 0;
    __syncthreads();

    int parts[SPLIT_ROUNDS];
    int dloc[SPLIT_ROUNDS];
    int myc = 0;                       // lane p (<8) accumulates partition-p count
    #pragma unroll
    for (int k = 0; k < SPLIT_ROUNDS; ++k) {
        int d = edst[base + k * 256 + tid];
        int p = d / PART_N;
        parts[k] = p;
        dloc[k]  = d - p * PART_N;
        #pragma unroll
        for (int pp = 0; pp < NPART; ++pp) {
            unsigned long long m = __ballot(p == pp);
            if (lane == pp) myc += __popcll(m);
        }
    }
    if (lane < NPART) atomicAdd(&lbase[lane], myc);
    __syncthreads();
    if (tid < NPART) lbase[tid] = atomicAdd(&pcur[tid], lbase[tid]);
    __syncthreads();

    #pragma unroll
    for (int k = 0; k < SPLIT_ROUNDS; ++k) {
        const int p = parts[k];
        int slot = 0;
        #pragma unroll
        for (int pp = 0; pp < NPART; ++pp) {
            unsigned long long m = __ballot(p == pp);
            int b = 0;
            if (lane == pp) b = atomicAdd(&lbase[pp], __popcll(m));  // LDS
            b = __shfl(b, pp, 64);
            if (p == pp) slot = b + __popcll(m & below);
        }
        int i = base + k * 256 + tid;
        int s = esrc[i];
        float w = 0.9f * ew[i];
        sbuf[slot] = make_int2((dloc[k] << 17) | s, __float_as_int(w));
    }
}

// ---------------------------------------------------------------------------
// Pass B: in-slice scatter. Blocks with blockIdx&7==p (round-robin block->XCD)
// stream partition p's sbuf range sequentially and scatter into its 3.2 MB
// csr slice. Read pressure on L2 is now 3.2 MB/XCD (was ~100 MB), so slice
// lines survive until all 8 entries arrive.
// ---------------------------------------------------------------------------
__global__ __launch_bounds__(256) void fill_b(
    const int2* __restrict__ sbuf, const int* __restrict__ row_start,
    int* __restrict__ pos, int2* __restrict__ csr)
{
    const int part = blockIdx.x & (NPART - 1);
    const int lo_e = row_start[part * PART_N];
    const int hi_e = row_start[(part + 1) * PART_N];   // row_start[N_NODES] valid
    const int stride = (FILL_GRID / NPART) * 256;
    for (int i = lo_e + (blockIdx.x >> 3) * 256 + (int)threadIdx.x; i < hi_e;
         i += stride) {
        int2 e = sbuf[i];
        int s = e.x & 0x1ffff;
        int d = part * PART_N + (((unsigned)e.x) >> 17);
        int q = atomicAdd(&pos[d], 1);
        csr[q] = make_int2(s, e.y);
    }
}

// In-row bitonic sort by src (locality only — correctness never depends on
// order). One wave per row; sorts first min(len,64) entries.
__global__ __launch_bounds__(256) void sort_rows(
    const int* __restrict__ row_start, int2* __restrict__ csr)
{
    const int node = blockIdx.x * 4 + (threadIdx.x >> 6);
    const int lane = threadIdx.x & 63;
    const int s0 = row_start[node];
    const int s1 = row_start[node + 1];
    int n = s1 - s0; if (n > 64) n = 64;
    int key = 0x7fffffff;
    int val = 0;
    if (lane < n) { int2 e = csr[s0 + lane]; key = e.x; val = e.y; }
    #pragma unroll
    for (int k = 2; k <= 64; k <<= 1) {
        #pragma unroll
        for (int j = k >> 1; j > 0; j >>= 1) {
            int pk = __shfl_xor(key, j, 64);
            int pv = __shfl_xor(val, j, 64);
            bool lower   = (lane & j) == 0;
            bool asc     = (lane & k) == 0;
            bool takeMin = (lower == asc);
            bool pick    = takeMin ? (pk < key) : (pk > key);
            if (pick) { key = pk; val = pv; }
        }
    }
    if (lane < n) csr[s0 + lane] = make_int2(key, val);
}

// ---------------------------------------------------------------------------
// Pull-based SpMM, bf16 z. One wave per dst node. 8 lanes x 16 B cover one
// z-row (64 bf16): one global_load_dwordx4 gathers 8 edges -> 8 distinct
// 128 B lines per VMEM instr. Unroll 4 => 32 edge-lines in flight per wave.
// Group g = lane>>3 owns edge slot; q = lane&7 owns features 8q..8q+7.
// Row-end reduction: 3 shfl_xor rounds over groups.
// NOTE: macro params named WV/ZV — .x/.y/.z/.w member tokens must NOT
// collide with parameter names (round-5 compile failure).
// ---------------------------------------------------------------------------
template <bool FINAL>
__global__ __launch_bounds__(256) void spmm_kernel(
    const int* __restrict__ row_start, const int2* __restrict__ csr,
    const ushort_t* __restrict__ zin, const ushort_t* __restrict__ ahb,
    void* __restrict__ zout)
{
    const int node = blockIdx.x * 4 + (threadIdx.x >> 6);  // 25000*4 == 100000
    const int lane = threadIdx.x & 63;
    const int g = lane >> 3;    // edge slot 0..7
    const int q = lane & 7;     // feature octet
    const int s0 = __builtin_amdgcn_readfirstlane(row_start[node]);
    const int s1 = __builtin_amdgcn_readfirstlane(row_start[node + 1]);

    float a0=0.f,a1=0.f,a2=0.f,a3=0.f,a4=0.f,a5=0.f,a6=0.f,a7=0.f;
    if (g == 0) {
        uint4 t = *(const uint4*)&ahb[node * 64 + 8 * q];
        a0 = bflo(t.x); a1 = bfhi(t.x); a2 = bflo(t.y); a3 = bfhi(t.y);
        a4 = bflo(t.z); a5 = bfhi(t.z); a6 = bflo(t.w); a7 = bfhi(t.w);
    }

#define FMA8(WV, ZV) do { \
        a0 = fmaf((WV), bflo((ZV).x), a0); a1 = fmaf((WV), bfhi((ZV).x), a1); \
        a2 = fmaf((WV), bflo((ZV).y), a2); a3 = fmaf((WV), bfhi((ZV).y), a3); \
        a4 = fmaf((WV), bflo((ZV).z), a4); a5 = fmaf((WV), bfhi((ZV).z), a5); \
        a6 = fmaf((WV), bflo((ZV).w), a6); a7 = fmaf((WV), bfhi((ZV).w), a7); \
    } while (0)

    int j = s0;
    for (; j + 32 <= s1; j += 32) {
        int2 e0 = csr[j + g];
        int2 e1 = csr[j + 8 + g];
        int2 e2 = csr[j + 16 + g];
        int2 e3 = csr[j + 24 + g];
        uint4 z0 = *(const uint4*)&zin[e0.x * 64 + 8 * q];
        uint4 z1 = *(const uint4*)&zin[e1.x * 64 + 8 * q];
        uint4 z2 = *(const uint4*)&zin[e2.x * 64 + 8 * q];
        uint4 z3 = *(const uint4*)&zin[e3.x * 64 + 8 * q];
        float w0 = __int_as_float(e0.y);
        float w1 = __int_as_float(e1.y);
        float w2 = __int_as_float(e2.y);
        float w3 = __int_as_float(e3.y);
        FMA8(w0, z0);
        FMA8(w1, z1);
        FMA8(w2, z2);
        FMA8(w3, z3);
    }
    for (; j < s1; j += 8) {
        int2 e = make_int2(0, 0);
        int jj = j + g;
        if (jj < s1) e = csr[jj];
        uint4 zt = *(const uint4*)&zin[e.x * 64 + 8 * q];
        float wt = __int_as_float(e.y);
        FMA8(wt, zt);
    }
#undef FMA8

    // reduce the 8 edge-slot groups (lane bits 3,4,5)
    #pragma unroll
    for (int m = 8; m <= 32; m <<= 1) {
        a0 += __shfl_xor(a0, m, 64); a1 += __shfl_xor(a1, m, 64);
        a2 += __shfl_xor(a2, m, 64); a3 += __shfl_xor(a3, m, 64);
        a4 += __shfl_xor(a4, m, 64); a5 += __shfl_xor(a5, m, 64);
        a6 += __shfl_xor(a6, m, 64); a7 += __shfl_xor(a7, m, 64);
    }

    if (g == 0) {
        if (FINAL) {
            float* op = (float*)zout + node * 64 + 8 * q;
            *(float4*)op       = make_float4(a0, a1, a2, a3);
            *(float4*)(op + 4) = make_float4(a4, a5, a6, a7);
        } else {
            uint4 pk;
            pk.x = packbf(a0, a1); pk.y = packbf(a2, a3);
            pk.z = packbf(a4, a5); pk.w = packbf(a6, a7);
            *(uint4*)&((ushort_t*)zout)[node * 64 + 8 * q] = pk;
        }
    }
}

// ---------------------------------------------------------------------------
extern "C" void kernel_launch(void* const* d_in, const int* in_sizes, int n_in,
                              void* d_out, int out_size, void* d_ws, size_t ws_size,
                              hipStream_t stream)
{
    const float* x    = (const float*)d_in[0];
    const int*   esrc = (const int*)d_in[1];
    const int*   edst = (const int*)d_in[2];
    const float* ew   = (const float*)d_in[3];
    const float* W1   = (const float*)d_in[4];
    const float* b1   = (const float*)d_in[5];
    const float* W2   = (const float*)d_in[6];
    const float* b2   = (const float*)d_in[7];
    float* out = (float*)d_out;

    // workspace layout (~65 MB). sbuf (25.6 MB) ALIASES ahb+hb: the CSR build
    // (split+fill_b) runs before mlp_mfma writes hb/ahb.
    char* p = (char*)d_ws;
    ushort_t* ahb = (ushort_t*)p;  p += (size_t)N_NODES * 64 * 2;   // 12.8M
    ushort_t* hb  = (ushort_t*)p;  p += (size_t)N_NODES * 64 * 2;   // 12.8M
    ushort_t* zB  = (ushort_t*)p;  p += (size_t)N_NODES * 64 * 2;   // 12.8M
    int2*  csr     = (int2*)p;     p += (size_t)N_EDGES * 8;        // 25.6M
    int* cnt       = (int*)p;      p += (size_t)N_NODES * 4;
    int* pos       = (int*)p;      p += (size_t)N_NODES * 4;
    int* row_start = (int*)p;      p += (size_t)(N_NODES + 1) * 4;
    int* bsum      = (int*)p;      p += (size_t)SCAN_B * 4;
    int* boff      = (int*)p;      p += (size_t)SCAN_B * 4;
    int* pcur      = (int*)p;      p += (size_t)NPART * 4;
    ushort_t* w1t  = (ushort_t*)p; p += (size_t)64 * KPAD * 2;      // 64 KB
    ushort_t* w2t  = (ushort_t*)p; p += (size_t)64 * 64 * 2;        // 8 KB
    int2* sbuf = (int2*)ahb;       // alias: 25.6 MB over ahb+hb

    const int EB = (N_EDGES + 255) / 256;

    hipLaunchKernelGGL(prep_weights, dim3((64 * KPAD + 64 * 64 + 255) / 256),
                       dim3(256), 0, stream, W1, W2, w1t, w2t);

    // CSR build first (sbuf aliases ahb/hb, so this precedes mlp)
    hipLaunchKernelGGL(zero_cnt, dim3(SCAN_B), dim3(256), 0, stream, cnt);
    hipLaunchKernelGGL(count_keys, dim3(EB), dim3(256), 0, stream, edst, cnt);
    hipLaunchKernelGGL(scan_block_sums, dim3(SCAN_B), dim3(256), 0, stream, cnt, bsum);
    hipLaunchKernelGGL(scan_partials, dim3(1), dim3(512), 0, stream, bsum, boff);
    hipLaunchKernelGGL(scan_final, dim3(SCAN_B), dim3(256), 0, stream,
                       cnt, boff, row_start, pos, pcur);
    hipLaunchKernelGGL(split_edges, dim3(SPLIT_GRID), dim3(256), 0, stream,
                       esrc, edst, ew, pcur, sbuf);
    hipLaunchKernelGGL(fill_b, dim3(FILL_GRID), dim3(256), 0, stream,
                       sbuf, row_start, pos, csr);
    hipLaunchKernelGGL(sort_rows, dim3(N_NODES / 4), dim3(256), 0, stream,
                       row_start, csr);

    // MLP after CSR build (frees the sbuf alias)
    hipLaunchKernelGGL(mlp_mfma, dim3((N_NODES + 63) / 64), dim3(256), 0, stream,
                       x, w1t, b1, w2t, b2, hb, ahb);

    // propagation: strict alternation. it even: ->zB, it odd: ->hb.
    // it=0: hb->zB; ... it=8: hb->zB; final (it=9): zB->out(fp32).
    const ushort_t* zi = hb;
    for (int it = 0; it < K_ITERS - 1; ++it) {
        ushort_t* zo = (it % 2 == 0) ? zB : hb;
        hipLaunchKernelGGL((spmm_kernel<false>), dim3(N_NODES / 4), dim3(256), 0, stream,
                           row_start, csr, zi, ahb, (void*)zo);
        zi = zo;
    }
    hipLaunchKernelGGL((spmm_kernel<true>), dim3(N_NODES / 4), dim3(256), 0, stream,
                       row_start, csr, zi, ahb, (void*)out);
}

// Round 5
// 1298.414 us; speedup vs baseline: 1.1076x; 1.0132x over previous
//
#include <hip/hip_runtime.h>

#define N_NODES 100000
#define N_EDGES 3200000
#define IN_F 500
#define HID 64
#define OUT_F 64
#define ALPHA 0.1f
#define K_ITERS 10
#define SCAN_B ((N_NODES + 255) / 256)   // 391

#define NPART 8                          // XCD count (m09)
#define PART_N (N_NODES / NPART)         // 12500
#define FILL_GRID 2048                   // 8 blocks/CU x 256 CU

#define SPLIT_CHUNK 2560                 // edges per block in split_edges
#define SPLIT_ROUNDS 10                  // 2560 / 256
#define SPLIT_GRID (N_EDGES / SPLIT_CHUNK)   // 1250 exactly

#define KPAD 512                // IN_F padded to MFMA K-step multiple

typedef unsigned short ushort_t;
typedef unsigned int uint_t;
typedef __attribute__((ext_vector_type(8))) short bf16x8;   // MFMA A/B frag (4 VGPR)
typedef __attribute__((ext_vector_type(4))) float f32x4;    // MFMA C/D frag

__device__ __forceinline__ float bf2f(ushort_t v) {
    union { uint_t u; float f; } c; c.u = ((uint_t)v) << 16; return c.f;
}
__device__ __forceinline__ ushort_t f2b(float f) {
    union { float f; uint_t u; } c; c.f = f;
    uint_t u = c.u + 0x7fffu + ((c.u >> 16) & 1u);   // round-to-nearest-even
    return (ushort_t)(u >> 16);
}
__device__ __forceinline__ float bflo(uint_t u) {
    union { uint_t u; float f; } c; c.u = u << 16; return c.f;
}
__device__ __forceinline__ float bfhi(uint_t u) {
    union { uint_t u; float f; } c; c.u = u & 0xffff0000u; return c.f;
}
__device__ __forceinline__ uint_t packbf(float a, float b) {
    return (uint_t)f2b(a) | ((uint_t)f2b(b) << 16);
}
__device__ __forceinline__ bf16x8 pack8(float4 a, float4 b) {
    bf16x8 r;
    r[0] = (short)f2b(a.x); r[1] = (short)f2b(a.y);
    r[2] = (short)f2b(a.z); r[3] = (short)f2b(a.w);
    r[4] = (short)f2b(b.x); r[5] = (short)f2b(b.y);
    r[6] = (short)f2b(b.z); r[7] = (short)f2b(b.w);
    return r;
}

// ---------------------------------------------------------------------------
// Weight prep: W1[500x64] -> w1t bf16 [64][512] (transposed, K zero-padded),
// W2[64x64] -> w2t bf16 [64][64] (transposed). B-frag for mfma_16x16x32 is
// lane l -> B[k=(l>>4)*8+e][col=l&15]; storing [col][k] makes each frag one
// contiguous 16 B load. Tiny one-shot kernel.
// ---------------------------------------------------------------------------
__global__ __launch_bounds__(256) void prep_weights(
    const float* __restrict__ W1, const float* __restrict__ W2,
    ushort_t* __restrict__ w1t, ushort_t* __restrict__ w2t)
{
    int i = blockIdx.x * 256 + threadIdx.x;
    if (i < 64 * KPAD) {
        int c = i >> 9, k = i & (KPAD - 1);
        float v = (k < IN_F) ? W1[k * HID + c] : 0.f;
        w1t[c * KPAD + k] = f2b(v);
    } else {
        int j = i - 64 * KPAD;
        if (j < 64 * 64) {
            int c = j >> 6, k = j & 63;
            w2t[c * 64 + k] = f2b(W2[k * OUT_F + c]);
        }
    }
}

// ---------------------------------------------------------------------------
// MFMA MLP: v = relu(x@W1+b1)@W2+b2 ; hb = bf16(v), ahb = bf16(ALPHA*v).
// Block = 256 (4 waves), 64 rows; wave w owns rows w*16..+15 (one M-tile).
// Round-4 post-mortem: VGPR_Count=32 starved the compiler into serializing
// the per-k-step x loads (latency-bound, 147 us @ 1 TB/s). Layer 1 is now
// straight-line with 16 explicit float4 load pairs (two 4-step chunks in
// flight, compile-time indices only): 16 global_load_dwordx4 issued before
// the first MFMA. k=480..512 tail is branchless zero-fill (w1t zero-padded;
// zeros finite; no OOB read for row 99999). hs tile XOR-swizzled
// (col ^ ((row&7)<<3)) to kill the 350K 16-lane/4-bank conflicts.
// ---------------------------------------------------------------------------
__global__ __launch_bounds__(256, 2) void mlp_mfma(
    const float* __restrict__ x, const ushort_t* __restrict__ w1t,
    const float* __restrict__ b1, const ushort_t* __restrict__ w2t,
    const float* __restrict__ b2, ushort_t* __restrict__ hb,
    ushort_t* __restrict__ ahb)
{
    __shared__ ushort_t hs[4][16][64];   // per-wave hidden tile, 8 KB total

    const int lane = threadIdx.x & 63;
    const int wid  = threadIdx.x >> 6;
    const int r16  = lane & 15;          // A-row / B-col within tile
    const int kg   = lane >> 4;          // k-group 0..3
    const int rowbase = blockIdx.x * 64 + wid * 16;

    int arow  = rowbase + r16;
    int lrow  = (arow < N_NODES) ? arow : (N_NODES - 1);   // clamp loads only
    const float* xr = x + (long)lrow * IN_F;

    f32x4 acc[4];
    #pragma unroll
    for (int t = 0; t < 4; ++t) acc[t] = (f32x4){0.f, 0.f, 0.f, 0.f};

    const float4 z4 = make_float4(0.f, 0.f, 0.f, 0.f);

#define XLD(PA, PB, KS) do {                                      \
        PA = *(const float4*)(xr + (KS) * 32 + kg * 8);           \
        PB = *(const float4*)(xr + (KS) * 32 + kg * 8 + 4);       \
    } while (0)
    // ks=15 covers k in [480,512): lane slice [480+kg*8, 480+kg*8+8).
    // xa valid iff 480+kg*8+4 <= 500 (kg<=2); xb valid iff +8 <= 500 (kg<=1).
    // Invalid slices -> 0 (finite; paired w1t columns are zero).
#define XLDT(PA, PB) do {                                         \
        PA = (kg <= 2) ? *(const float4*)(xr + 480 + kg * 8) : z4;\
        PB = (kg <= 1) ? *(const float4*)(xr + 484 + kg * 8) : z4;\
    } while (0)
#define XMM(PA, PB, KS) do {                                      \
        bf16x8 af_ = pack8(PA, PB);                               \
        _Pragma("unroll")                                         \
        for (int t = 0; t < 4; ++t) {                             \
            bf16x8 bw_ = *(const bf16x8*)&w1t[(t * 16 + r16) * KPAD + (KS) * 32 + kg * 8]; \
            acc[t] = __builtin_amdgcn_mfma_f32_16x16x32_bf16(af_, bw_, acc[t], 0, 0, 0);   \
        }                                                         \
    } while (0)

    float4 a0,b0,a1,b1_,a2,b2_,a3,b3,a4,b4,a5,b5,a6,b6,a7,b7;
    XLD(a0,b0,0);  XLD(a1,b1_,1); XLD(a2,b2_,2); XLD(a3,b3,3);    // chunk 0
    XLD(a4,b4,4);  XLD(a5,b5,5);  XLD(a6,b6,6);  XLD(a7,b7,7);    // chunk 1
    XMM(a0,b0,0);  XMM(a1,b1_,1); XMM(a2,b2_,2); XMM(a3,b3,3);
    XLD(a0,b0,8);  XLD(a1,b1_,9); XLD(a2,b2_,10); XLD(a3,b3,11);  // chunk 2
    XMM(a4,b4,4);  XMM(a5,b5,5);  XMM(a6,b6,6);  XMM(a7,b7,7);
    XLD(a4,b4,12); XLD(a5,b5,13); XLD(a6,b6,14); XLDT(a7,b7);     // chunk 3 (tail)
    XMM(a0,b0,8);  XMM(a1,b1_,9); XMM(a2,b2_,10); XMM(a3,b3,11);
    XMM(a4,b4,12); XMM(a5,b5,13); XMM(a6,b6,14); XMM(a7,b7,15);
#undef XLD
#undef XLDT
#undef XMM

    // bias + relu, stash hidden tile. C/D layout: row=kg*4+r, col=t*16+r16.
    // XOR-swizzle (16B-unit granularity in ushort idx: col ^ ((row&7)<<3)).
    #pragma unroll
    for (int t = 0; t < 4; ++t) {
        float bb = b1[t * 16 + r16];
        #pragma unroll
        for (int r = 0; r < 4; ++r) {
            float h = fmaxf(acc[t][r] + bb, 0.f);
            int row = kg * 4 + r;
            int col = (t * 16 + r16) ^ ((row & 7) << 3);
            hs[wid][row][col] = f2b(h);
        }
    }
    __syncthreads();

    f32x4 acc2[4];
    #pragma unroll
    for (int t = 0; t < 4; ++t) acc2[t] = (f32x4){0.f, 0.f, 0.f, 0.f};

    #pragma unroll
    for (int ks = 0; ks < 2; ++ks) {
        int colr = (ks * 32 + kg * 8) ^ ((r16 & 7) << 3);
        bf16x8 ha = *(const bf16x8*)&hs[wid][r16][colr];
        #pragma unroll
        for (int t = 0; t < 4; ++t) {
            bf16x8 wb = *(const bf16x8*)&w2t[(t * 16 + r16) * 64 + ks * 32 + kg * 8];
            acc2[t] = __builtin_amdgcn_mfma_f32_16x16x32_bf16(ha, wb, acc2[t], 0, 0, 0);
        }
    }

    #pragma unroll
    for (int t = 0; t < 4; ++t) {
        float bb = b2[t * 16 + r16];
        #pragma unroll
        for (int r = 0; r < 4; ++r) {
            int orow = rowbase + kg * 4 + r;
            if (orow < N_NODES) {
                float v = acc2[t][r] + bb;
                hb[orow * 64 + t * 16 + r16]  = f2b(v);
                ahb[orow * 64 + t * 16 + r16] = f2b(ALPHA * v);
            }
        }
    }
}

// ---------------------------------------------------------------------------
// CSR build: count -> 2-level exclusive scan -> partition split -> in-slice
// scatter -> row sort
// ---------------------------------------------------------------------------
__global__ __launch_bounds__(256) void zero_cnt(int* __restrict__ cnt)
{
    int i = blockIdx.x * 256 + threadIdx.x;
    if (i < N_NODES) cnt[i] = 0;
}

__global__ __launch_bounds__(256) void count_keys(
    const int* __restrict__ key, int* __restrict__ cnt)
{
    int i = blockIdx.x * 256 + threadIdx.x;
    if (i < N_EDGES) atomicAdd(&cnt[key[i]], 1);
}

__global__ __launch_bounds__(256) void scan_block_sums(
    const int* __restrict__ cnt, int* __restrict__ bsum)
{
    int i = blockIdx.x * 256 + threadIdx.x;
    int v = (i < N_NODES) ? cnt[i] : 0;
    for (int off = 32; off; off >>= 1) v += __shfl_down(v, off);
    __shared__ int ws_[4];
    if ((threadIdx.x & 63) == 0) ws_[threadIdx.x >> 6] = v;
    __syncthreads();
    if (threadIdx.x == 0) bsum[blockIdx.x] = ws_[0] + ws_[1] + ws_[2] + ws_[3];
}

__global__ __launch_bounds__(512) void scan_partials(
    const int* __restrict__ bsum, int* __restrict__ boff)
{
    int t = threadIdx.x;
    int v = (t < SCAN_B) ? bsum[t] : 0;
    int lane = t & 63, w = t >> 6;
    int x = v;
    for (int off = 1; off < 64; off <<= 1) {
        int y = __shfl_up(x, off);
        if (lane >= off) x += y;
    }
    __shared__ int wsum[8];
    if (lane == 63) wsum[w] = x;
    __syncthreads();
    if (w == 0) {
        int s = (lane < 8) ? wsum[lane] : 0;
        for (int off = 1; off < 8; off <<= 1) {
            int y = __shfl_up(s, off);
            if (lane >= off) s += y;
        }
        if (lane < 8) wsum[lane] = s;
    }
    __syncthreads();
    int wpre = (w == 0) ? 0 : wsum[w - 1];
    if (t < SCAN_B) boff[t] = wpre + x - v;
}

// also seeds pcur[p] = row_start[p*PART_N] (exact partition bases for split)
__global__ __launch_bounds__(256) void scan_final(
    const int* __restrict__ cnt, const int* __restrict__ boff,
    int* __restrict__ row_start, int* __restrict__ pos,
    int* __restrict__ pcur)
{
    int i = blockIdx.x * 256 + threadIdx.x;
    int v = (i < N_NODES) ? cnt[i] : 0;
    int lane = threadIdx.x & 63, w = threadIdx.x >> 6;
    int x = v;
    for (int off = 1; off < 64; off <<= 1) {
        int y = __shfl_up(x, off);
        if (lane >= off) x += y;
    }
    __shared__ int wsum[4];
    if (lane == 63) wsum[w] = x;
    __syncthreads();
    int wpre = 0;
    for (int ww = 0; ww < w; ++ww) wpre += wsum[ww];
    int excl = wpre + x - v;
    int r = boff[blockIdx.x] + excl;
    if (i < N_NODES) {
        row_start[i] = r; pos[i] = r;
        if ((i % PART_N) == 0) pcur[i / PART_N] = r;
    }
    if (i == 0) row_start[N_NODES] = N_EDGES;
}

// ---------------------------------------------------------------------------
// Pass A: partition split. Each block owns 2560 consecutive edges.
// Sweep 1 counts per-partition via wave ballots; block reserves regions with
// 8 global atomics. Sweep 2 writes edges compacted into partition-grouped
// sbuf: dense per-block runs -> full-line writes by construction.
// Entry: (dst_local<<17 | src, w). sbuf ALIASES ahb+hb — runs before mlp.
// ---------------------------------------------------------------------------
__global__ __launch_bounds__(256) void split_edges(
    const int* __restrict__ esrc, const int* __restrict__ edst,
    const float* __restrict__ ew, int* __restrict__ pcur,
    int2* __restrict__ sbuf)
{
    __shared__ int lbase[NPART];
    const int tid  = threadIdx.x;
    const int lane = tid & 63;
    const int base = blockIdx.x * SPLIT_CHUNK;
    const unsigned long long below = (lane == 63) ? ~0ull >> 1
                                                  : (1ull << lane) - 1ull;

    if (tid < NPART) lbase[tid] = 0;
    __syncthreads();

    int parts[SPLIT_ROUNDS];
    int dloc[SPLIT_ROUNDS];
    int myc = 0;                       // lane p (<8) accumulates partition-p count
    #pragma unroll
    for (int k = 0; k < SPLIT_ROUNDS; ++k) {
        int d = edst[base + k * 256 + tid];
        int p = d / PART_N;
        parts[k] = p;
        dloc[k]  = d - p * PART_N;
        #pragma unroll
        for (int pp = 0; pp < NPART; ++pp) {
            unsigned long long m = __ballot(p == pp);
            if (lane == pp) myc += __popcll(m);
        }
    }
    if (lane < NPART) atomicAdd(&lbase[lane], myc);
    __syncthreads();
    if (tid < NPART) lbase[tid] = atomicAdd(&pcur[tid], lbase[tid]);
    __syncthreads();

    #pragma unroll
    for (int k = 0; k < SPLIT_ROUNDS; ++k) {
        const int p = parts[k];
        int slot = 0;
        #pragma unroll
        for (int pp = 0; pp < NPART; ++pp) {
            unsigned long long m = __ballot(p == pp);
            int b = 0;
            if (lane == pp) b = atomicAdd(&lbase[pp], __popcll(m));  // LDS
            b = __shfl(b, pp, 64);
            if (p == pp) slot = b + __popcll(m & below);
        }
        int i = base + k * 256 + tid;
        int s = esrc[i];
        float w = 0.9f * ew[i];
        sbuf[slot] = make_int2((dloc[k] << 17) | s, __float_as_int(w));
    }
}

// ---------------------------------------------------------------------------
// Pass B: in-slice scatter. Blocks with blockIdx&7==p (round-robin block->XCD)
// stream partition p's sbuf range sequentially and scatter into its 3.2 MB
// csr slice.
// ---------------------------------------------------------------------------
__global__ __launch_bounds__(256) void fill_b(
    const int2* __restrict__ sbuf, const int* __restrict__ row_start,
    int* __restrict__ pos, int2* __restrict__ csr)
{
    const int part = blockIdx.x & (NPART - 1);
    const int lo_e = row_start[part * PART_N];
    const int hi_e = row_start[(part + 1) * PART_N];   // row_start[N_NODES] valid
    const int stride = (FILL_GRID / NPART) * 256;
    for (int i = lo_e + (blockIdx.x >> 3) * 256 + (int)threadIdx.x; i < hi_e;
         i += stride) {
        int2 e = sbuf[i];
        int s = e.x & 0x1ffff;
        int d = part * PART_N + (((unsigned)e.x) >> 17);
        int q = atomicAdd(&pos[d], 1);
        csr[q] = make_int2(s, e.y);
    }
}

// In-row bitonic sort by src (locality only — correctness never depends on
// order). One wave per row; sorts first min(len,64) entries.
__global__ __launch_bounds__(256) void sort_rows(
    const int* __restrict__ row_start, int2* __restrict__ csr)
{
    const int node = blockIdx.x * 4 + (threadIdx.x >> 6);
    const int lane = threadIdx.x & 63;
    const int s0 = row_start[node];
    const int s1 = row_start[node + 1];
    int n = s1 - s0; if (n > 64) n = 64;
    int key = 0x7fffffff;
    int val = 0;
    if (lane < n) { int2 e = csr[s0 + lane]; key = e.x; val = e.y; }
    #pragma unroll
    for (int k = 2; k <= 64; k <<= 1) {
        #pragma unroll
        for (int j = k >> 1; j > 0; j >>= 1) {
            int pk = __shfl_xor(key, j, 64);
            int pv = __shfl_xor(val, j, 64);
            bool lower   = (lane & j) == 0;
            bool asc     = (lane & k) == 0;
            bool takeMin = (lower == asc);
            bool pick    = takeMin ? (pk < key) : (pk > key);
            if (pick) { key = pk; val = pv; }
        }
    }
    if (lane < n) csr[s0 + lane] = make_int2(key, val);
}

// ---------------------------------------------------------------------------
// Pull-based SpMM, bf16 z. One wave per dst node. 8 lanes x 16 B cover one
// z-row (64 bf16): one global_load_dwordx4 gathers 8 edges -> 8 distinct
// 128 B lines per VMEM instr. Unroll 4 => 32 edge-lines in flight per wave.
// Group g = lane>>3 owns edge slot; q = lane&7 owns features 8q..8q+7.
// Row-end reduction: 3 shfl_xor rounds over groups.
// NOTE: macro params named WV/ZV — .x/.y/.z/.w member tokens must NOT
// collide with parameter names (round-5 compile failure).
// ---------------------------------------------------------------------------
template <bool FINAL>
__global__ __launch_bounds__(256) void spmm_kernel(
    const int* __restrict__ row_start, const int2* __restrict__ csr,
    const ushort_t* __restrict__ zin, const ushort_t* __restrict__ ahb,
    void* __restrict__ zout)
{
    const int node = blockIdx.x * 4 + (threadIdx.x >> 6);  // 25000*4 == 100000
    const int lane = threadIdx.x & 63;
    const int g = lane >> 3;    // edge slot 0..7
    const int q = lane & 7;     // feature octet
    const int s0 = __builtin_amdgcn_readfirstlane(row_start[node]);
    const int s1 = __builtin_amdgcn_readfirstlane(row_start[node + 1]);

    float a0=0.f,a1=0.f,a2=0.f,a3=0.f,a4=0.f,a5=0.f,a6=0.f,a7=0.f;
    if (g == 0) {
        uint4 t = *(const uint4*)&ahb[node * 64 + 8 * q];
        a0 = bflo(t.x); a1 = bfhi(t.x); a2 = bflo(t.y); a3 = bfhi(t.y);
        a4 = bflo(t.z); a5 = bfhi(t.z); a6 = bflo(t.w); a7 = bfhi(t.w);
    }

#define FMA8(WV, ZV) do { \
        a0 = fmaf((WV), bflo((ZV).x), a0); a1 = fmaf((WV), bfhi((ZV).x), a1); \
        a2 = fmaf((WV), bflo((ZV).y), a2); a3 = fmaf((WV), bfhi((ZV).y), a3); \
        a4 = fmaf((WV), bflo((ZV).z), a4); a5 = fmaf((WV), bfhi((ZV).z), a5); \
        a6 = fmaf((WV), bflo((ZV).w), a6); a7 = fmaf((WV), bfhi((ZV).w), a7); \
    } while (0)

    int j = s0;
    for (; j + 32 <= s1; j += 32) {
        int2 e0 = csr[j + g];
        int2 e1 = csr[j + 8 + g];
        int2 e2 = csr[j + 16 + g];
        int2 e3 = csr[j + 24 + g];
        uint4 z0 = *(const uint4*)&zin[e0.x * 64 + 8 * q];
        uint4 z1 = *(const uint4*)&zin[e1.x * 64 + 8 * q];
        uint4 z2 = *(const uint4*)&zin[e2.x * 64 + 8 * q];
        uint4 z3 = *(const uint4*)&zin[e3.x * 64 + 8 * q];
        float w0 = __int_as_float(e0.y);
        float w1 = __int_as_float(e1.y);
        float w2 = __int_as_float(e2.y);
        float w3 = __int_as_float(e3.y);
        FMA8(w0, z0);
        FMA8(w1, z1);
        FMA8(w2, z2);
        FMA8(w3, z3);
    }
    for (; j < s1; j += 8) {
        int2 e = make_int2(0, 0);
        int jj = j + g;
        if (jj < s1) e = csr[jj];
        uint4 zt = *(const uint4*)&zin[e.x * 64 + 8 * q];
        float wt = __int_as_float(e.y);
        FMA8(wt, zt);
    }
#undef FMA8

    // reduce the 8 edge-slot groups (lane bits 3,4,5)
    #pragma unroll
    for (int m = 8; m <= 32; m <<= 1) {
        a0 += __shfl_xor(a0, m, 64); a1 += __shfl_xor(a1, m, 64);
        a2 += __shfl_xor(a2, m, 64); a3 += __shfl_xor(a3, m, 64);
        a4 += __shfl_xor(a4, m, 64); a5 += __shfl_xor(a5, m, 64);
        a6 += __shfl_xor(a6, m, 64); a7 += __shfl_xor(a7, m, 64);
    }

    if (g == 0) {
        if (FINAL) {
            float* op = (float*)zout + node * 64 + 8 * q;
            *(float4*)op       = make_float4(a0, a1, a2, a3);
            *(float4*)(op + 4) = make_float4(a4, a5, a6, a7);
        } else {
            uint4 pk;
            pk.x = packbf(a0, a1); pk.y = packbf(a2, a3);
            pk.z = packbf(a4, a5); pk.w = packbf(a6, a7);
            *(uint4*)&((ushort_t*)zout)[node * 64 + 8 * q] = pk;
        }
    }
}

// ---------------------------------------------------------------------------
extern "C" void kernel_launch(void* const* d_in, const int* in_sizes, int n_in,
                              void* d_out, int out_size, void* d_ws, size_t ws_size,
                              hipStream_t stream)
{
    const float* x    = (const float*)d_in[0];
    const int*   esrc = (const int*)d_in[1];
    const int*   edst = (const int*)d_in[2];
    const float* ew   = (const float*)d_in[3];
    const float* W1   = (const float*)d_in[4];
    const float* b1   = (const float*)d_in[5];
    const float* W2   = (const float*)d_in[6];
    const float* b2   = (const float*)d_in[7];
    float* out = (float*)d_out;

    // workspace layout (~65 MB). sbuf (25.6 MB) ALIASES ahb+hb: the CSR build
    // (split+fill_b) runs before mlp_mfma writes hb/ahb.
    char* p = (char*)d_ws;
    ushort_t* ahb = (ushort_t*)p;  p += (size_t)N_NODES * 64 * 2;   // 12.8M
    ushort_t* hb  = (ushort_t*)p;  p += (size_t)N_NODES * 64 * 2;   // 12.8M
    ushort_t* zB  = (ushort_t*)p;  p += (size_t)N_NODES * 64 * 2;   // 12.8M
    int2*  csr     = (int2*)p;     p += (size_t)N_EDGES * 8;        // 25.6M
    int* cnt       = (int*)p;      p += (size_t)N_NODES * 4;
    int* pos       = (int*)p;      p += (size_t)N_NODES * 4;
    int* row_start = (int*)p;      p += (size_t)(N_NODES + 1) * 4;
    int* bsum      = (int*)p;      p += (size_t)SCAN_B * 4;
    int* boff      = (int*)p;      p += (size_t)SCAN_B * 4;
    int* pcur      = (int*)p;      p += (size_t)NPART * 4;
    ushort_t* w1t  = (ushort_t*)p; p += (size_t)64 * KPAD * 2;      // 64 KB
    ushort_t* w2t  = (ushort_t*)p; p += (size_t)64 * 64 * 2;        // 8 KB
    int2* sbuf = (int2*)ahb;       // alias: 25.6 MB over ahb+hb

    const int EB = (N_EDGES + 255) / 256;

    hipLaunchKernelGGL(prep_weights, dim3((64 * KPAD + 64 * 64 + 255) / 256),
                       dim3(256), 0, stream, W1, W2, w1t, w2t);

    // CSR build first (sbuf aliases ahb/hb, so this precedes mlp)
    hipLaunchKernelGGL(zero_cnt, dim3(SCAN_B), dim3(256), 0, stream, cnt);
    hipLaunchKernelGGL(count_keys, dim3(EB), dim3(256), 0, stream, edst, cnt);
    hipLaunchKernelGGL(scan_block_sums, dim3(SCAN_B), dim3(256), 0, stream, cnt, bsum);
    hipLaunchKernelGGL(scan_partials, dim3(1), dim3(512), 0, stream, bsum, boff);
    hipLaunchKernelGGL(scan_final, dim3(SCAN_B), dim3(256), 0, stream,
                       cnt, boff, row_start, pos, pcur);
    hipLaunchKernelGGL(split_edges, dim3(SPLIT_GRID), dim3(256), 0, stream,
                       esrc, edst, ew, pcur, sbuf);
    hipLaunchKernelGGL(fill_b, dim3(FILL_GRID), dim3(256), 0, stream,
                       sbuf, row_start, pos, csr);
    hipLaunchKernelGGL(sort_rows, dim3(N_NODES / 4), dim3(256), 0, stream,
                       row_start, csr);

    // MLP after CSR build (frees the sbuf alias)
    hipLaunchKernelGGL(mlp_mfma, dim3((N_NODES + 63) / 64), dim3(256), 0, stream,
                       x, w1t, b1, w2t, b2, hb, ahb);

    // propagation: strict alternation. it even: ->zB, it odd: ->hb.
    // it=0: hb->zB; ... it=8: hb->zB; final (it=9): zB->out(fp32).
    const ushort_t* zi = hb;
    for (int it = 0; it < K_ITERS - 1; ++it) {
        ushort_t* zo = (it % 2 == 0) ? zB : hb;
        hipLaunchKernelGGL((spmm_kernel<false>), dim3(N_NODES / 4), dim3(256), 0, stream,
                           row_start, csr, zi, ahb, (void*)zo);
        zi = zo;
    }
    hipLaunchKernelGGL((spmm_kernel<true>), dim3(N_NODES / 4), dim3(256), 0, stream,
                       row_start, csr, zi, ahb, (void*)out);
}